// Round 3
// baseline (271.456 us; speedup 1.0000x reference)
//
#include <hip/hip_runtime.h>
#include <hip/hip_bf16.h>
#include <cstdint>
#include <cstddef>

#define M_DIM 4096
#define N_DIM 4096
#define K_DIM 4096
#define NT    (K_DIM / 64)   // 64 K-tiles of BK=64

using f32x4   = __attribute__((ext_vector_type(4))) float;
using bf16x8  = __attribute__((ext_vector_type(8))) short;   // 8 bf16 in 4 VGPRs
using float4v = __attribute__((ext_vector_type(4))) float;

__device__ __forceinline__ ushort f32_to_bf16_rne(float f) {
    uint32_t u = __builtin_bit_cast(uint32_t, f);
    uint32_t rnd = 0x7FFFu + ((u >> 16) & 1u);
    return (ushort)((u + rnd) >> 16);
}

__device__ __forceinline__ void gload_lds16(const void* g, void* l) {
    __builtin_amdgcn_global_load_lds(
        (const __attribute__((address_space(1))) uint32_t*)g,
        (__attribute__((address_space(3))) uint32_t*)l, 16, 0, 0);
}

// ---------------- pass 1a: x (f32) -> bf16, row-major M x K ----------------
__global__ __launch_bounds__(256) void cvt_x_kernel(const float* __restrict__ x,
                                                    ushort* __restrict__ xq,
                                                    int n8) {
    int idx = blockIdx.x * blockDim.x + threadIdx.x;
    int stride = gridDim.x * blockDim.x;
    for (int i = idx; i < n8; i += stride) {
        const float4v* p = (const float4v*)(x + (size_t)i * 8);
        float4v v0 = p[0];
        float4v v1 = p[1];
        bf16x8 o;
        o[0] = (short)f32_to_bf16_rne(v0[0]);
        o[1] = (short)f32_to_bf16_rne(v0[1]);
        o[2] = (short)f32_to_bf16_rne(v0[2]);
        o[3] = (short)f32_to_bf16_rne(v0[3]);
        o[4] = (short)f32_to_bf16_rne(v1[0]);
        o[5] = (short)f32_to_bf16_rne(v1[1]);
        o[6] = (short)f32_to_bf16_rne(v1[2]);
        o[7] = (short)f32_to_bf16_rne(v1[3]);
        *(bf16x8*)(xq + (size_t)i * 8) = o;
    }
}

// ------- pass 1b: W (K x N, f32) -> sign -> bf16, TRANSPOSED to N x K -------
__global__ __launch_bounds__(256) void sign_wt_kernel(const float* __restrict__ W,
                                                      ushort* __restrict__ WqT) {
    __shared__ ushort tile[32][34];
    int j0 = blockIdx.x * 32;
    int k0 = blockIdx.y * 32;
    int tx = threadIdx.x;
    int ty = threadIdx.y;
#pragma unroll
    for (int i = 0; i < 4; ++i) {
        int kk = ty + i * 8;
        float w = W[(size_t)(k0 + kk) * N_DIM + (j0 + tx)];
        tile[kk][tx] = (w > 0.f) ? (ushort)0x3F80
                     : (w < 0.f) ? (ushort)0xBF80 : (ushort)0x0000;
    }
    __syncthreads();
#pragma unroll
    for (int i = 0; i < 4; ++i) {
        int jj = ty + i * 8;
        WqT[(size_t)(j0 + jj) * K_DIM + (k0 + tx)] = tile[tx][jj];
    }
}

// ------------- pass 2: 256x256-tile 8-phase bf16 MFMA GEMM (T1..T5) -------------
// One-phase ds_read read-ahead: each phase issues the NEXT phase's operand reads;
// MFMA consumes registers loaded a phase earlier (compiler emits counted lgkmcnt).

#define STAGE_A(p, h, kt) do {                                                   \
    const ushort* _g = Abase + (size_t)((h) * 128) * K_DIM + (kt) * 64;          \
    gload_lds16(_g, &lds[(p) * 16384 + (h) * 8192 + ldso]);                      \
    gload_lds16(_g + (size_t)64 * K_DIM,                                         \
                &lds[(p) * 16384 + (h) * 8192 + 4096 + ldso]);                   \
} while (0)

#define STAGE_B(p, h, kt) do {                                                   \
    const ushort* _g = Bbase + (size_t)((h) * 128) * K_DIM + (kt) * 64;          \
    gload_lds16(_g, &lds[32768 + (p) * 16384 + (h) * 8192 + ldso]);              \
    gload_lds16(_g + (size_t)64 * K_DIM,                                         \
                &lds[32768 + (p) * 16384 + (h) * 8192 + 4096 + ldso]);           \
} while (0)

#define RD_A(p, mh, mq, kk)                                                      \
    (*(const bf16x8*)(ldsc + (p) * 32768 + aB + (mh) * 8192 + (mq) * 2048 +      \
                      ((kk) ? koff1 : koff0)))
#define RD_B(p, nh, nq, kk)                                                      \
    (*(const bf16x8*)(ldsc + (p) * 32768 + bB + (nh) * 4096 + (nq) * 2048 +      \
                      ((kk) ? koff1 : koff0)))

#define MFMA_QUAD(mh, nh, Aarr, Barr) do {                                       \
    __builtin_amdgcn_s_setprio(1);                                               \
    _Pragma("unroll")                                                            \
    for (int mq = 0; mq < 4; ++mq)                                               \
        _Pragma("unroll")                                                        \
        for (int nq = 0; nq < 2; ++nq)                                           \
            _Pragma("unroll")                                                    \
            for (int kk = 0; kk < 2; ++kk)                                       \
                acc[(mh) * 4 + mq][(nh) * 2 + nq] =                              \
                    __builtin_amdgcn_mfma_f32_16x16x32_bf16(                     \
                        Aarr[mq][kk], Barr[nq][kk],                              \
                        acc[(mh) * 4 + mq][(nh) * 2 + nq], 0, 0, 0);             \
    __builtin_amdgcn_s_setprio(0);                                               \
} while (0)

// TILE(kt, p, pn, BC, BN): p = this tile's buffer, pn = other buffer,
// BC = this tile's B0 regs, BN = next tile's B0 regs (double-banked).
#define TILE(kt, p, pn, BC, BN) do {                                             \
    /* q0: operands (aX,BC) pre-read last tile; read-ahead bH = B1[p] */         \
    _Pragma("unroll")                                                            \
    for (int nq = 0; nq < 2; ++nq) {                                             \
        bH[nq][0] = RD_B(p, 1, nq, 0); bH[nq][1] = RD_B(p, 1, nq, 1);            \
    }                                                                            \
    __builtin_amdgcn_s_barrier();                                                \
    MFMA_QUAD(0, 0, aX, BC);                                                     \
    __builtin_amdgcn_s_barrier();                                                \
    /* q1: read-ahead aY = A1[p] */                                              \
    _Pragma("unroll")                                                            \
    for (int mq = 0; mq < 4; ++mq) {                                             \
        aY[mq][0] = RD_A(p, 1, mq, 0); aY[mq][1] = RD_A(p, 1, mq, 1);            \
    }                                                                            \
    __builtin_amdgcn_s_barrier();                                                \
    MFMA_QUAD(0, 1, aX, bH);                                                     \
    __builtin_amdgcn_s_barrier();                                                \
    /* q2: stage B(kt+2) into p (all B[p] reads completed by q1-end barrier) */  \
    if ((kt) + 2 < NT) { STAGE_B(p, 0, (kt) + 2); STAGE_B(p, 1, (kt) + 2); }     \
    __builtin_amdgcn_s_barrier();                                                \
    MFMA_QUAD(1, 1, aY, bH);                                                     \
    __builtin_amdgcn_s_barrier();                                                \
    /* q3: stage A(kt+2); drain so kt+1 landed (all waves, via barrier);         \
           pre-read next tile's q0 operands from pn, overlapped with MFMA */     \
    if ((kt) + 2 < NT) { STAGE_A(p, 0, (kt) + 2); STAGE_A(p, 1, (kt) + 2); }     \
    if ((kt) + 2 < NT) { asm volatile("s_waitcnt vmcnt(8)" ::: "memory"); }      \
    else               { asm volatile("s_waitcnt vmcnt(0)" ::: "memory"); }      \
    __builtin_amdgcn_s_barrier();                                                \
    __builtin_amdgcn_sched_barrier(0);                                           \
    if ((kt) + 1 < NT) {                                                         \
        _Pragma("unroll")                                                        \
        for (int mq = 0; mq < 4; ++mq) {                                         \
            aX[mq][0] = RD_A(pn, 0, mq, 0); aX[mq][1] = RD_A(pn, 0, mq, 1);      \
        }                                                                        \
        _Pragma("unroll")                                                        \
        for (int nq = 0; nq < 2; ++nq) {                                         \
            BN[nq][0] = RD_B(pn, 0, nq, 0); BN[nq][1] = RD_B(pn, 0, nq, 1);      \
        }                                                                        \
    }                                                                            \
    MFMA_QUAD(1, 0, aY, BC);                                                     \
    __builtin_amdgcn_s_barrier();                                                \
} while (0)

__global__ __launch_bounds__(512, 1) void gemm_bin_kernel(const ushort* __restrict__ A,  // M x K bf16
                                                          const ushort* __restrict__ B,  // N x K bf16
                                                          const float* __restrict__ bias,
                                                          float* __restrict__ C) {
    __shared__ __align__(16) ushort lds[65536];   // 128 KiB: A[2][2][128][64], B[2][2][128][64]

    // T1: XCD-aware bijective swizzle (256 wgs, 256 % 8 == 0)
    int bid  = blockIdx.x;
    int swz  = (bid & 7) * 32 + (bid >> 3);
    int brow = (swz >> 4) << 8;
    int bcol = (swz & 15) << 8;

    int t    = threadIdx.x;
    int lane = t & 63;
    int wid  = t >> 6;
    int wr   = wid >> 2;   // 0..1  (M half)
    int wc   = wid & 3;    // 0..3  (N quarter)

    // ---- staging invariants (T2: inverse-swizzled global source, linear LDS dest) ----
    int sr   = lane >> 3;                    // row-within-8
    int k0   = ((lane & 7) ^ sr) << 3;       // swizzle-permuted k chunk (elements)
    int ldso = wid * 512 + lane * 8;         // linear dest offset (elements)
    int grow = wid * 8 + sr;                 // row within 128-row half

    const ushort* Abase = A + (size_t)(brow + grow) * K_DIM + k0;
    const ushort* Bbase = B + (size_t)(bcol + grow) * K_DIM + k0;

    // ---- fragment-read invariants (swizzled ds_read_b128) ----
    int lrow  = lane & 15;
    int klo   = lane >> 4;
    int sx    = (lrow & 7) << 4;
    int koff0 = (klo * 16) ^ sx;
    int koff1 = (64 + klo * 16) ^ sx;
    const char* ldsc = (const char*)lds;
    int aB = wr * 16384 + lrow * 128;
    int bB = 65536 + (wc >> 1) * 16384 + (wc & 1) * 8192 + lrow * 128;

    f32x4 acc[8][4];
#pragma unroll
    for (int i = 0; i < 8; ++i)
#pragma unroll
        for (int j = 0; j < 4; ++j)
            acc[i][j] = (f32x4){0.f, 0.f, 0.f, 0.f};

    bf16x8 aX[4][2], aY[4][2], bLa[2][2], bLb[2][2], bH[2][2];

    // prologue: stage tiles 0,1; drain to tile 0 landed; pre-read tile0 q0 operands
    STAGE_A(0, 0, 0); STAGE_A(0, 1, 0); STAGE_B(0, 0, 0); STAGE_B(0, 1, 0);
    STAGE_A(1, 0, 1); STAGE_A(1, 1, 1); STAGE_B(1, 0, 1); STAGE_B(1, 1, 1);
    asm volatile("s_waitcnt vmcnt(8)" ::: "memory");
    __builtin_amdgcn_s_barrier();
    __builtin_amdgcn_sched_barrier(0);
#pragma unroll
    for (int mq = 0; mq < 4; ++mq) {
        aX[mq][0] = RD_A(0, 0, mq, 0); aX[mq][1] = RD_A(0, 0, mq, 1);
    }
#pragma unroll
    for (int nq = 0; nq < 2; ++nq) {
        bLa[nq][0] = RD_B(0, 0, nq, 0); bLa[nq][1] = RD_B(0, 0, nq, 1);
    }

    for (int kt2 = 0; kt2 < NT; kt2 += 2) {
        TILE(kt2, 0, 1, bLa, bLb);
        TILE(kt2 + 1, 1, 0, bLb, bLa);
    }

    // epilogue: C/D layout col=lane&15, row=(lane>>4)*4+reg
    int crow = brow + wr * 128 + klo * 4;
    int ccol = bcol + wc * 64 + lrow;
#pragma unroll
    for (int ni = 0; ni < 4; ++ni) {
        int col = ccol + (ni >> 1) * 32 + (ni & 1) * 16;
        float bv = bias[col];
#pragma unroll
        for (int mi = 0; mi < 8; ++mi) {
            int row = crow + (mi >> 2) * 64 + (mi & 3) * 16;
#pragma unroll
            for (int r = 0; r < 4; ++r)
                C[(size_t)(row + r) * N_DIM + col] = acc[mi][ni][r] + bv;
        }
    }
}

extern "C" void kernel_launch(void* const* d_in, const int* in_sizes, int n_in,
                              void* d_out, int out_size, void* d_ws, size_t ws_size,
                              hipStream_t stream) {
    const float* x = (const float*)d_in[0];   // (4096, 4096) f32
    const float* W = (const float*)d_in[1];   // (4096, 4096) f32
    const float* b = (const float*)d_in[2];   // (4096,) f32
    float* out = (float*)d_out;               // (4096, 4096) f32

    ushort* xq  = (ushort*)d_ws;                               // 32 MB: X as bf16 (M x K)
    ushort* WqT = (ushort*)d_ws + (size_t)M_DIM * K_DIM;       // 32 MB: sign(W) bf16, N x K

    cvt_x_kernel<<<2048, 256, 0, stream>>>(x, xq, M_DIM * K_DIM / 8);
    sign_wt_kernel<<<dim3(N_DIM / 32, K_DIM / 32), dim3(32, 8), 0, stream>>>(W, WqT);
    gemm_bin_kernel<<<dim3(256), dim3(512), 0, stream>>>(xq, WqT, b, out);
}

// Round 5
// 103.305 us; speedup vs baseline: 2.6277x; 2.6277x over previous
//
#include <hip/hip_runtime.h>
#include <hip/hip_bf16.h>
#include <cstdint>
#include <cstddef>

#define M_DIM 4096
#define N_DIM 4096
#define K_DIM 4096
#define NT    (K_DIM / 128)   // 32 K-tiles of BK=128

using i32x4  = __attribute__((ext_vector_type(4))) int;
using s8x16  = __attribute__((ext_vector_type(16))) char;
using float4v = __attribute__((ext_vector_type(4))) float;

__device__ __forceinline__ void gload_lds16(const void* g, void* l) {
    __builtin_amdgcn_global_load_lds(
        (const __attribute__((address_space(1))) uint32_t*)g,
        (__attribute__((address_space(3))) uint32_t*)l, 16, 0, 0);
}

__device__ __forceinline__ i32x4 mfma_i8(i32x4 a, i32x4 b, i32x4 c) {
    return __builtin_amdgcn_mfma_i32_16x16x64_i8(a, b, c, 0, 0, 0);
}

// ------------- pass 1a: x (f32) -> i8  q = clamp(rint(32x), ±127) -------------
__global__ __launch_bounds__(256) void cvt_x_kernel(const float* __restrict__ x,
                                                    char* __restrict__ xq,
                                                    int n16) {
    int idx = blockIdx.x * blockDim.x + threadIdx.x;
    int stride = gridDim.x * blockDim.x;
    for (int i = idx; i < n16; i += stride) {
        const float4v* p = (const float4v*)(x + (size_t)i * 16);
        s8x16 o;
#pragma unroll
        for (int v = 0; v < 4; ++v) {
            float4v f = p[v];
#pragma unroll
            for (int j = 0; j < 4; ++j) {
                float q = __builtin_rintf(f[j] * 32.0f);
                q = fminf(127.0f, fmaxf(-127.0f, q));
                o[v * 4 + j] = (char)(int)q;
            }
        }
        *(s8x16*)(xq + (size_t)i * 16) = o;
    }
}

// ------ pass 1b: W (K x N, f32) -> sign -> i8, TRANSPOSED to N x K ------
__global__ __launch_bounds__(256) void sign_wt_kernel(const float* __restrict__ W,
                                                      char* __restrict__ WqT) {
    __shared__ char tile[64][68];   // 68B stride: odd dword step -> ~2-way max
    int j0 = blockIdx.x * 64;       // N coordinate
    int k0 = blockIdx.y * 64;       // K coordinate
    int tx = threadIdx.x;           // 0..63
    int ty = threadIdx.y;           // 0..3
#pragma unroll
    for (int i = 0; i < 16; ++i) {
        int kk = ty + i * 4;
        float w = W[(size_t)(k0 + kk) * N_DIM + (j0 + tx)];
        tile[kk][tx] = (char)((w > 0.f) - (w < 0.f));
    }
    __syncthreads();
#pragma unroll
    for (int i = 0; i < 16; ++i) {
        int jj = ty + i * 4;
        WqT[(size_t)(j0 + jj) * K_DIM + (k0 + tx)] = tile[tx][jj];
    }
}

// ---------------- pass 2: 256x256-tile i8 MFMA GEMM, BK=128 ----------------
// R2-verified 8-barrier/tile schedule; c-major 1024B-granule LDS (fragment
// reads = base + lane*16, conflict-free); counted vmcnt(8); setprio on MFMA.
// Stage ledger (64-row blocks, liveness = union over all waves):
//   A blk 0,2 (mh0 of wr0/wr1): last read q0 -> stage q1
//   B blk 0..3 (wc=b):          last read q1 -> stage q2
//   A blk 1,3 (mh1):            last read q2 -> stage q3

#define STAGE_A(p, b, kt)                                                        \
    gload_lds16(AbaseG + (size_t)((b) * 64) * K_DIM + (size_t)(kt) * 128,        \
                lds + (p) * 32768 + (b) * 8192 + (t << 4))
#define STAGE_B(p, b, kt)                                                        \
    gload_lds16(BbaseG + (size_t)((b) * 64) * K_DIM + (size_t)(kt) * 128,        \
                lds + 65536 + (p) * 32768 + (b) * 8192 + (t << 4))

#define RD_A(p, mh, mq, kk)                                                      \
    (*(const i32x4*)(ldsc + (p) * 32768 + aB + (mh) * 8192 + (mq) * 2048 +       \
                     (kk) * 1024))
#define RD_B(p, nh, nq, kk)                                                      \
    (*(const i32x4*)(ldsc + 65536 + (p) * 32768 + bB + (nh) * 4096 +             \
                     (nq) * 2048 + (kk) * 1024))

#define MFMA_QUAD(mh, nh, Barr) do {                                             \
    __builtin_amdgcn_s_setprio(1);                                               \
    _Pragma("unroll")                                                            \
    for (int mq = 0; mq < 4; ++mq)                                               \
        _Pragma("unroll")                                                        \
        for (int nq = 0; nq < 2; ++nq)                                           \
            _Pragma("unroll")                                                    \
            for (int kk = 0; kk < 2; ++kk)                                       \
                acc[(mh) * 4 + mq][(nh) * 2 + nq] =                              \
                    mfma_i8(aF[mq][kk], Barr[nq][kk],                            \
                            acc[(mh) * 4 + mq][(nh) * 2 + nq]);                  \
    __builtin_amdgcn_s_setprio(0);                                               \
} while (0)

#define SCHED0 __builtin_amdgcn_sched_barrier(0)

#define TILE(kt, p) do {                                                         \
    /* q0: read bL (B nh0) + aF (A mh0); MFMA (0,0) */                           \
    _Pragma("unroll")                                                            \
    for (int nq = 0; nq < 2; ++nq) {                                             \
        bL[nq][0] = RD_B(p, 0, nq, 0); bL[nq][1] = RD_B(p, 0, nq, 1);            \
    }                                                                            \
    _Pragma("unroll")                                                            \
    for (int mq = 0; mq < 4; ++mq) {                                             \
        aF[mq][0] = RD_A(p, 0, mq, 0); aF[mq][1] = RD_A(p, 0, mq, 1);            \
    }                                                                            \
    SCHED0; __builtin_amdgcn_s_barrier();                                        \
    asm volatile("s_waitcnt lgkmcnt(0)");                                        \
    MFMA_QUAD(0, 0, bL);                                                         \
    SCHED0; __builtin_amdgcn_s_barrier();                                        \
    /* q1: read bH (B nh1); stage A blk 0,2 (freed at q0-end); MFMA (0,1) */     \
    _Pragma("unroll")                                                            \
    for (int nq = 0; nq < 2; ++nq) {                                             \
        bH[nq][0] = RD_B(p, 1, nq, 0); bH[nq][1] = RD_B(p, 1, nq, 1);            \
    }                                                                            \
    if ((kt) + 2 < NT) { STAGE_A(p, 0, (kt) + 2); STAGE_A(p, 2, (kt) + 2); }     \
    SCHED0; __builtin_amdgcn_s_barrier();                                        \
    asm volatile("s_waitcnt lgkmcnt(0)");                                        \
    MFMA_QUAD(0, 1, bH);                                                         \
    SCHED0; __builtin_amdgcn_s_barrier();                                        \
    /* q2: read aF=A mh1; stage B blk 0..3 (freed at q1-end); MFMA (1,1) */      \
    _Pragma("unroll")                                                            \
    for (int mq = 0; mq < 4; ++mq) {                                             \
        aF[mq][0] = RD_A(p, 1, mq, 0); aF[mq][1] = RD_A(p, 1, mq, 1);            \
    }                                                                            \
    if ((kt) + 2 < NT) {                                                         \
        STAGE_B(p, 0, (kt) + 2); STAGE_B(p, 1, (kt) + 2);                        \
        STAGE_B(p, 2, (kt) + 2); STAGE_B(p, 3, (kt) + 2);                        \
    }                                                                            \
    SCHED0; __builtin_amdgcn_s_barrier();                                        \
    asm volatile("s_waitcnt lgkmcnt(0)");                                        \
    MFMA_QUAD(1, 1, bH);                                                         \
    SCHED0; __builtin_amdgcn_s_barrier();                                        \
    /* q3: stage A blk 1,3 (freed at q2-end); MFMA (1,0); counted vmcnt */       \
    if ((kt) + 2 < NT) { STAGE_A(p, 1, (kt) + 2); STAGE_A(p, 3, (kt) + 2); }     \
    SCHED0; __builtin_amdgcn_s_barrier();                                        \
    MFMA_QUAD(1, 0, bL);                                                         \
    if ((kt) + 2 < NT) { asm volatile("s_waitcnt vmcnt(8)" ::: "memory"); }      \
    else               { asm volatile("s_waitcnt vmcnt(0)" ::: "memory"); }      \
    SCHED0; __builtin_amdgcn_s_barrier();                                        \
} while (0)

__global__ __launch_bounds__(512, 1) void gemm_bin_kernel(const char* __restrict__ A,  // M x K i8
                                                          const char* __restrict__ B,  // N x K i8
                                                          const float* __restrict__ bias,
                                                          float* __restrict__ C) {
    // 128 KiB: A[2][16 rg][2 kk][1024B c-major granule], B same at +65536
    __shared__ __align__(16) unsigned char lds[131072];

    // T1: XCD-aware bijective swizzle (256 wgs, 256 % 8 == 0)
    int bid  = blockIdx.x;
    int swz  = (bid & 7) * 32 + (bid >> 3);
    int brow = (swz >> 4) << 8;
    int bcol = (swz & 15) << 8;

    int t    = threadIdx.x;
    int l    = t & 63;
    int wid  = t >> 6;
    int wr   = wid >> 2;   // 0..1  (M half)
    int wc   = wid & 3;    // 0..3  (N quarter)

    // staging: thread t -> granule slot; source pre-permuted to c-major granules
    int growI = ((t >> 7) << 4) + (t & 15);               // row within 64-row block
    int gkI   = (((t >> 6) & 1) << 6) + (((t >> 4) & 3) << 4);  // k byte offset in BK=128

    const char* AbaseG = A + (size_t)(brow + growI) * K_DIM + gkI;
    const char* BbaseG = B + (size_t)(bcol + growI) * K_DIM + gkI;

    // fragment reads: granule-contiguous, base + lane*16
    const char* ldsc = (const char*)lds;
    int aB = wr * 16384 + (l << 4);
    int bB = wc * 8192  + (l << 4);

    i32x4 acc[8][4];
#pragma unroll
    for (int i = 0; i < 8; ++i)
#pragma unroll
        for (int j = 0; j < 4; ++j)
            acc[i][j] = (i32x4){0, 0, 0, 0};

    i32x4 aF[4][2], bL[2][2], bH[2][2];

    // prologue: stage tiles 0 (buf0) and 1 (buf1); drain so tile 0 landed
#pragma unroll
    for (int b = 0; b < 4; ++b) { STAGE_A(0, b, 0); }
#pragma unroll
    for (int b = 0; b < 4; ++b) { STAGE_B(0, b, 0); }
#pragma unroll
    for (int b = 0; b < 4; ++b) { STAGE_A(1, b, 1); }
#pragma unroll
    for (int b = 0; b < 4; ++b) { STAGE_B(1, b, 1); }
    asm volatile("s_waitcnt vmcnt(8)" ::: "memory");
    __builtin_amdgcn_s_barrier();

    for (int kt2 = 0; kt2 < NT; kt2 += 2) {
        TILE(kt2, 0);
        TILE(kt2 + 1, 1);
    }

    // epilogue: C/D layout col=lane&15, row=(lane>>4)*4+reg; dequant 1/32
    int klo  = l >> 4;
    int lrow = l & 15;
    int crow = brow + wr * 128 + klo * 4;
    int ccol = bcol + wc * 64 + lrow;
#pragma unroll
    for (int ni = 0; ni < 4; ++ni) {
        int col = ccol + (ni >> 1) * 32 + (ni & 1) * 16;
        float bv = bias[col];
#pragma unroll
        for (int mi = 0; mi < 8; ++mi) {
            int row = crow + (mi >> 2) * 64 + (mi & 3) * 16;
#pragma unroll
            for (int r = 0; r < 4; ++r)
                C[(size_t)(row + r) * N_DIM + col] =
                    (float)acc[mi][ni][r] * 0.03125f + bv;
        }
    }
}

extern "C" void kernel_launch(void* const* d_in, const int* in_sizes, int n_in,
                              void* d_out, int out_size, void* d_ws, size_t ws_size,
                              hipStream_t stream) {
    const float* x = (const float*)d_in[0];   // (4096, 4096) f32
    const float* W = (const float*)d_in[1];   // (4096, 4096) f32
    const float* b = (const float*)d_in[2];   // (4096,) f32
    float* out = (float*)d_out;               // (4096, 4096) f32

    char* xq  = (char*)d_ws;                              // 16 MB: x as i8 (M x K), scale 32
    char* WqT = (char*)d_ws + (size_t)M_DIM * K_DIM;      // 16 MB: sign(W) i8, N x K

    cvt_x_kernel<<<2048, 256, 0, stream>>>(x, xq, M_DIM * K_DIM / 16);
    sign_wt_kernel<<<dim3(N_DIM / 64, K_DIM / 64), dim3(64, 4), 0, stream>>>(W, WqT);
    gemm_bin_kernel<<<dim3(256), dim3(512), 0, stream>>>(xq, WqT, b, out);
}

// Round 6
// 102.690 us; speedup vs baseline: 2.6435x; 1.0060x over previous
//
#include <hip/hip_runtime.h>
#include <hip/hip_bf16.h>
#include <cstdint>
#include <cstddef>

#define M_DIM 4096
#define N_DIM 4096
#define K_DIM 4096
#define NT    (K_DIM / 128)   // 32 K-tiles of BK=128

using i32x4  = __attribute__((ext_vector_type(4))) int;
using s8x16  = __attribute__((ext_vector_type(16))) char;
using float4v = __attribute__((ext_vector_type(4))) float;

__device__ __forceinline__ void gload_lds16(const void* g, void* l) {
    __builtin_amdgcn_global_load_lds(
        (const __attribute__((address_space(1))) uint32_t*)g,
        (__attribute__((address_space(3))) uint32_t*)l, 16, 0, 0);
}

__device__ __forceinline__ i32x4 mfma_i8(i32x4 a, i32x4 b, i32x4 c) {
    return __builtin_amdgcn_mfma_i32_16x16x64_i8(a, b, c, 0, 0, 0);
}

// ------------- pass 1a: x (f32) -> i8  q = clamp(rint(32x), ±127) -------------
__global__ __launch_bounds__(256) void cvt_x_kernel(const float* __restrict__ x,
                                                    char* __restrict__ xq,
                                                    int n16) {
    int idx = blockIdx.x * blockDim.x + threadIdx.x;
    int stride = gridDim.x * blockDim.x;
    for (int i = idx; i < n16; i += stride) {
        const float4v* p = (const float4v*)(x + (size_t)i * 16);
        s8x16 o;
#pragma unroll
        for (int v = 0; v < 4; ++v) {
            float4v f = p[v];
#pragma unroll
            for (int j = 0; j < 4; ++j) {
                float q = __builtin_rintf(f[j] * 32.0f);
                q = fminf(127.0f, fmaxf(-127.0f, q));
                o[v * 4 + j] = (char)(int)q;
            }
        }
        *(s8x16*)(xq + (size_t)i * 16) = o;
    }
}

// ------ pass 1b: W (K x N, f32) -> sign -> i8, TRANSPOSED to N x K ------
__global__ __launch_bounds__(256) void sign_wt_kernel(const float* __restrict__ W,
                                                      char* __restrict__ WqT) {
    __shared__ char tile[64][68];   // 68B stride: odd dword step -> ~2-way max
    int j0 = blockIdx.x * 64;       // N coordinate
    int k0 = blockIdx.y * 64;       // K coordinate
    int tx = threadIdx.x;           // 0..63
    int ty = threadIdx.y;           // 0..3
#pragma unroll
    for (int i = 0; i < 16; ++i) {
        int kk = ty + i * 4;
        float w = W[(size_t)(k0 + kk) * N_DIM + (j0 + tx)];
        tile[kk][tx] = (char)((w > 0.f) - (w < 0.f));
    }
    __syncthreads();
#pragma unroll
    for (int i = 0; i < 16; ++i) {
        int jj = ty + i * 4;
        WqT[(size_t)(j0 + jj) * K_DIM + (k0 + tx)] = tile[tx][jj];
    }
}

// ---------------- pass 2: 256x256-tile i8 MFMA GEMM, BK=128 ----------------
// 4-phase / 4-barrier schedule, compiler-counted lgkmcnt (no explicit drains).
// c-major 1024B-granule LDS (fragment reads = base + lane*16, conflict-free).
// Stage ledger (64-row blocks, liveness = union over all waves' reads):
//   A blk 0,2 (mh0): last read q0 -> stage q1 (guard: q0-end barrier)
//   B blk 0..3:      last read q1 -> stage q2 (guard: q1-end barrier)
//   A blk 1,3 (mh1): last read q2 -> stage q3 (guard: q2-end barrier)
// Landing gate: vmcnt(8) at q3 end (kt+1's 8 landed, kt+2's 8 in flight).

#define STAGE_A(p, b, kt)                                                        \
    gload_lds16(AbaseG + (size_t)((b) * 64) * K_DIM + (size_t)(kt) * 128,        \
                lds + (p) * 32768 + (b) * 8192 + (t << 4))
#define STAGE_B(p, b, kt)                                                        \
    gload_lds16(BbaseG + (size_t)((b) * 64) * K_DIM + (size_t)(kt) * 128,        \
                lds + 65536 + (p) * 32768 + (b) * 8192 + (t << 4))

#define RD_A(p, mh, mq, kk)                                                      \
    (*(const i32x4*)(ldsc + (p) * 32768 + aB + (mh) * 8192 + (mq) * 2048 +       \
                     (kk) * 1024))
#define RD_B(p, nh, nq, kk)                                                      \
    (*(const i32x4*)(ldsc + 65536 + (p) * 32768 + bB + (nh) * 4096 +             \
                     (nq) * 2048 + (kk) * 1024))

#define MFMA_QUAD(mh, nh, Barr) do {                                             \
    __builtin_amdgcn_s_setprio(1);                                               \
    _Pragma("unroll")                                                            \
    for (int mq = 0; mq < 4; ++mq)                                               \
        _Pragma("unroll")                                                        \
        for (int nq = 0; nq < 2; ++nq)                                           \
            _Pragma("unroll")                                                    \
            for (int kk = 0; kk < 2; ++kk)                                       \
                acc[(mh) * 4 + mq][(nh) * 2 + nq] =                              \
                    mfma_i8(aF[mq][kk], Barr[nq][kk],                            \
                            acc[(mh) * 4 + mq][(nh) * 2 + nq]);                  \
    __builtin_amdgcn_s_setprio(0);                                               \
} while (0)

#define SCHED0 __builtin_amdgcn_sched_barrier(0)

#define TILE(kt, p) do {                                                         \
    /* q0: read bL (B nh0, consumption-first) + aF (A mh0); MFMA (0,0).          \
       Counted lgkm: first MFMA waits only its own operands. */                  \
    _Pragma("unroll")                                                            \
    for (int nq = 0; nq < 2; ++nq) {                                             \
        bL[nq][0] = RD_B(p, 0, nq, 0); bL[nq][1] = RD_B(p, 0, nq, 1);            \
    }                                                                            \
    _Pragma("unroll")                                                            \
    for (int mq = 0; mq < 4; ++mq) {                                             \
        aF[mq][0] = RD_A(p, 0, mq, 0); aF[mq][1] = RD_A(p, 0, mq, 1);            \
    }                                                                            \
    MFMA_QUAD(0, 0, bL);                                                         \
    __builtin_amdgcn_s_barrier();                                                \
    SCHED0;                                                                      \
    /* q1: stage A blk 0,2 (freed at q0-end); read bH (B nh1); MFMA (0,1) */     \
    if ((kt) + 2 < NT) { STAGE_A(p, 0, (kt) + 2); STAGE_A(p, 2, (kt) + 2); }     \
    _Pragma("unroll")                                                            \
    for (int nq = 0; nq < 2; ++nq) {                                             \
        bH[nq][0] = RD_B(p, 1, nq, 0); bH[nq][1] = RD_B(p, 1, nq, 1);            \
    }                                                                            \
    MFMA_QUAD(0, 1, bH);                                                         \
    __builtin_amdgcn_s_barrier();                                                \
    SCHED0;                                                                      \
    /* q2: stage B blk 0..3 (freed at q1-end); read aF = A mh1; MFMA (1,1) */    \
    if ((kt) + 2 < NT) {                                                         \
        STAGE_B(p, 0, (kt) + 2); STAGE_B(p, 1, (kt) + 2);                        \
        STAGE_B(p, 2, (kt) + 2); STAGE_B(p, 3, (kt) + 2);                        \
    }                                                                            \
    _Pragma("unroll")                                                            \
    for (int mq = 0; mq < 4; ++mq) {                                             \
        aF[mq][0] = RD_A(p, 1, mq, 0); aF[mq][1] = RD_A(p, 1, mq, 1);            \
    }                                                                            \
    MFMA_QUAD(1, 1, bH);                                                         \
    __builtin_amdgcn_s_barrier();                                                \
    SCHED0;                                                                      \
    /* q3: stage A blk 1,3 (freed at q2-end); MFMA (1,0) (all regs);             \
       counted vmcnt: kt+1's 8 oldest landed, kt+2's 8 stay in flight */         \
    if ((kt) + 2 < NT) { STAGE_A(p, 1, (kt) + 2); STAGE_A(p, 3, (kt) + 2); }     \
    MFMA_QUAD(1, 0, bL);                                                         \
    if ((kt) + 2 < NT) { asm volatile("s_waitcnt vmcnt(8)" ::: "memory"); }      \
    else               { asm volatile("s_waitcnt vmcnt(0)" ::: "memory"); }      \
    __builtin_amdgcn_s_barrier();                                                \
    SCHED0;                                                                      \
} while (0)

__global__ __launch_bounds__(512, 1) void gemm_bin_kernel(const char* __restrict__ A,  // M x K i8
                                                          const char* __restrict__ B,  // N x K i8
                                                          const float* __restrict__ bias,
                                                          float* __restrict__ C) {
    // 128 KiB: A[2][16 rg][2 kk][1024B c-major granule], B same at +65536
    __shared__ __align__(16) unsigned char lds[131072];

    // T1: XCD-aware bijective swizzle (256 wgs, 256 % 8 == 0)
    int bid  = blockIdx.x;
    int swz  = (bid & 7) * 32 + (bid >> 3);
    int brow = (swz >> 4) << 8;
    int bcol = (swz & 15) << 8;

    int t    = threadIdx.x;
    int l    = t & 63;
    int wid  = t >> 6;
    int wr   = wid >> 2;   // 0..1  (M half)
    int wc   = wid & 3;    // 0..3  (N quarter)

    // staging: thread t -> granule slot; source pre-permuted to c-major granules
    int growI = ((t >> 7) << 4) + (t & 15);                     // row within 64-row block
    int gkI   = (((t >> 6) & 1) << 6) + (((t >> 4) & 3) << 4);  // k byte offset in BK=128

    const char* AbaseG = A + (size_t)(brow + growI) * K_DIM + gkI;
    const char* BbaseG = B + (size_t)(bcol + growI) * K_DIM + gkI;

    // fragment reads: granule-contiguous, base + lane*16
    const char* ldsc = (const char*)lds;
    int aB = wr * 16384 + (l << 4);
    int bB = wc * 8192  + (l << 4);

    i32x4 acc[8][4];
#pragma unroll
    for (int i = 0; i < 8; ++i)
#pragma unroll
        for (int j = 0; j < 4; ++j)
            acc[i][j] = (i32x4){0, 0, 0, 0};

    i32x4 aF[4][2], bL[2][2], bH[2][2];

    // prologue: stage tiles 0 (buf0) and 1 (buf1); drain so tile 0 landed
#pragma unroll
    for (int b = 0; b < 4; ++b) { STAGE_A(0, b, 0); }
#pragma unroll
    for (int b = 0; b < 4; ++b) { STAGE_B(0, b, 0); }
#pragma unroll
    for (int b = 0; b < 4; ++b) { STAGE_A(1, b, 1); }
#pragma unroll
    for (int b = 0; b < 4; ++b) { STAGE_B(1, b, 1); }
    asm volatile("s_waitcnt vmcnt(8)" ::: "memory");
    __builtin_amdgcn_s_barrier();
    SCHED0;

    for (int kt2 = 0; kt2 < NT; kt2 += 2) {
        TILE(kt2, 0);
        TILE(kt2 + 1, 1);
    }

    // epilogue: C/D layout col=lane&15, row=(lane>>4)*4+reg; dequant 1/32
    int klo  = l >> 4;
    int lrow = l & 15;
    int crow = brow + wr * 128 + klo * 4;
    int ccol = bcol + wc * 64 + lrow;
#pragma unroll
    for (int ni = 0; ni < 4; ++ni) {
        int col = ccol + (ni >> 1) * 32 + (ni & 1) * 16;
        float bv = bias[col];
#pragma unroll
        for (int mi = 0; mi < 8; ++mi) {
            int row = crow + (mi >> 2) * 64 + (mi & 3) * 16;
#pragma unroll
            for (int r = 0; r < 4; ++r)
                C[(size_t)(row + r) * N_DIM + col] =
                    (float)acc[mi][ni][r] * 0.03125f + bv;
        }
    }
}

extern "C" void kernel_launch(void* const* d_in, const int* in_sizes, int n_in,
                              void* d_out, int out_size, void* d_ws, size_t ws_size,
                              hipStream_t stream) {
    const float* x = (const float*)d_in[0];   // (4096, 4096) f32
    const float* W = (const float*)d_in[1];   // (4096, 4096) f32
    const float* b = (const float*)d_in[2];   // (4096,) f32
    float* out = (float*)d_out;               // (4096, 4096) f32

    char* xq  = (char*)d_ws;                              // 16 MB: x as i8 (M x K), scale 32
    char* WqT = (char*)d_ws + (size_t)M_DIM * K_DIM;      // 16 MB: sign(W) i8, N x K

    cvt_x_kernel<<<2048, 256, 0, stream>>>(x, xq, M_DIM * K_DIM / 16);
    sign_wt_kernel<<<dim3(N_DIM / 64, K_DIM / 64), dim3(64, 4), 0, stream>>>(W, WqT);
    gemm_bin_kernel<<<dim3(256), dim3(512), 0, stream>>>(xq, WqT, b, out);
}